// Round 5
// baseline (697.002 us; speedup 1.0000x reference)
//
#include <hip/hip_runtime.h>
#include <hip/hip_bf16.h>
#include <stdint.h>

// HadLinear: out = blockFWHT1024(x)/32 @ W^T  ==  x @ (blockFWHT1024(W rows)/32)^T
// (1) x f32->bf16, (2) Wh = FWHT(W)/32 -> bf16, (3) bf16 MFMA GEMM.
// GEMM: 8-phase, BM=BN=256, BK=64, 8 waves (2Mx4N), 2-buffer LDS, XOR swizzle.
// R5: one-phase REGISTER READ-AHEAD — ds_reads for phase p+1 issue before
// MFMA(p) (ping-pong frag sets e/o), so LDS drain overlaps the MFMA cluster.
// New-tile transitions (ph4/ph8) get VMC(2)+extra barrier so no wave reads a
// tile before ALL waves' global_load_lds landed (cross-wave vmcnt race fix).

typedef __attribute__((ext_vector_type(8))) short    short8;
typedef __attribute__((ext_vector_type(4))) float    f32x4;
typedef __attribute__((ext_vector_type(8))) uint16_t u16x8;

static constexpr int MDIM = 16384;
static constexpr int NDIM = 4096;
static constexpr int KDIM = 4096;
static constexpr int BM = 256, BN = 256, BK = 64;
static constexpr int NT = KDIM / BK;   // 64 K-tiles, 32 iterations

__device__ __forceinline__ uint16_t f2bf(float f) {
  union { float f; uint32_t u; } c; c.f = f;
  uint32_t u = c.u;
  return (uint16_t)((u + 0x7FFFu + ((u >> 16) & 1u)) >> 16);
}

__global__ __launch_bounds__(256) void cvt_x_kernel(const float* __restrict__ x,
                                                    uint16_t* __restrict__ xb, int n8) {
  int stride = gridDim.x * blockDim.x;
  for (int t = blockIdx.x * blockDim.x + threadIdx.x; t < n8; t += stride) {
    const float4* p = reinterpret_cast<const float4*>(x + (size_t)t * 8);
    float4 a = p[0], b = p[1];
    u16x8 o;
    o[0] = f2bf(a.x); o[1] = f2bf(a.y); o[2] = f2bf(a.z); o[3] = f2bf(a.w);
    o[4] = f2bf(b.x); o[5] = f2bf(b.y); o[6] = f2bf(b.z); o[7] = f2bf(b.w);
    *reinterpret_cast<u16x8*>(xb + (size_t)t * 8) = o;
  }
}

__global__ __launch_bounds__(256) void fwht_w_kernel(const float* __restrict__ W,
                                                     uint16_t* __restrict__ Wh) {
  __shared__ float s[1024];
  const int tid = threadIdx.x;
  const size_t base = (size_t)blockIdx.x * 1024;
  reinterpret_cast<float4*>(s)[tid] = reinterpret_cast<const float4*>(W + base)[tid];
  __syncthreads();
  for (int h = 1; h < 1024; h <<= 1) {
    #pragma unroll
    for (int pp = 0; pp < 2; ++pp) {
      int p = tid + pp * 256;
      int q = p & (h - 1);
      int i = ((p - q) << 1) | q;
      float a = s[i], b = s[i + h];
      s[i] = a + b;
      s[i + h] = a - b;
    }
    __syncthreads();
  }
  #pragma unroll
  for (int pp = 0; pp < 4; ++pp) {
    int i = tid + pp * 256;
    Wh[base + i] = f2bf(s[i] * 0.03125f);
  }
}

// ---------------- 8-phase GEMM: C[M,N] = A[M,K] * B[N,K]^T ----------------
// LDS tile: 256 rows x 8 chunks(16B), chunk (r,c') holds global c = c'^((r>>1)&7).

#define FENCE asm volatile("" ::: "memory")
#define SBAR  do { FENCE; __builtin_amdgcn_s_barrier(); \
                   __builtin_amdgcn_sched_barrier(0); } while (0)
#define SCHED0 __builtin_amdgcn_sched_barrier(0)
#define VMC(n) do { asm volatile("s_waitcnt vmcnt(" #n ")" ::: "memory"); \
                    __builtin_amdgcn_sched_barrier(0); } while (0)

#define LDA4(DST, BUF, MLO, KOFF)                                              \
  do { _Pragma("unroll")                                                       \
    for (int m_ = 0; m_ < 4; ++m_)                                             \
      DST[m_] = *(const short8*)(aRd + (BUF)*32768 + ((MLO)+m_)*2048 + (KOFF)); \
  } while (0)

#define LDB4(DST, BUF, KOFF)                                                   \
  do { _Pragma("unroll")                                                       \
    for (int n_ = 0; n_ < 4; ++n_)                                             \
      DST[n_] = *(const short8*)(bRd + (BUF)*32768 + n_*2048 + (KOFF));        \
  } while (0)

#define MF16(AF, BF, MB)                                                       \
  do { __builtin_amdgcn_s_setprio(1);                                          \
    _Pragma("unroll")                                                          \
    for (int m_ = 0; m_ < 4; ++m_)                                             \
      _Pragma("unroll")                                                        \
      for (int n_ = 0; n_ < 4; ++n_)                                           \
        acc[(MB)+m_][n_] = __builtin_amdgcn_mfma_f32_16x16x32_bf16(            \
            AF[m_], BF[n_], acc[(MB)+m_][n_], 0, 0, 0);                        \
    __builtin_amdgcn_s_setprio(0);                                             \
  } while (0)

// Iteration i: tiles 2i (buf0, ph1-4), T1=2i+1 (buf1, ph5-8).
// Stages: ph1 T1.A.h0 | ph2 T1.A.h1+B.h1 | ph4 T2.B.h0 | ph5 T2.A.h0
//         ph6 T2.A.h1+B.h1 | ph8 T3.B.h0   (T2=2i+2 buf0, T3=2i+3 buf1)
// Read-ahead: reads(p+1) issue before MFMA(p). Frag ping-pong: e = phases
// {1,2,5,6} pairs, o = {3,4,7,8}. New-tile reads (ph5 @ph4, ph1' @ph8) sit
// behind VMC(2)+SBAR so all waves' staging landed first.
#define ITER(T1, T2, T3, FIN)                                                  \
  do {                                                                         \
    /* ph1 */ SBAR;                                                            \
    stageA(1, 0, (T1));                                                        \
    LDA4(aHe, 0, 4, k0off);                                                    \
    SCHED0; MF16(aLe, bKe, 0);                                                 \
    /* ph2 */ SBAR;                                                            \
    stageA(1, 1, (T1)); stageB(1, 1, (T1));                                    \
    LDB4(bKo, 0, k1off); LDA4(aLo, 0, 0, k1off);                               \
    SCHED0; MF16(aHe, bKe, 4);                                                 \
    /* ph3 */ SBAR;                                                            \
    LDA4(aHo, 0, 4, k1off);                                                    \
    SCHED0; MF16(aLo, bKo, 0);                                                 \
    /* ph4 */ SBAR;                                                            \
    if (!(FIN)) stageB(0, 0, (T2));                                            \
    if (FIN) { VMC(0); } else { VMC(2); }                                      \
    SBAR;   /* all waves' T1 loads landed -> buf1 safe to read */              \
    LDB4(bKe, 1, k0off); LDA4(aLe, 1, 0, k0off);                               \
    SCHED0; MF16(aHo, bKo, 4);                                                 \
    /* ph5 */ SBAR;                                                            \
    if (!(FIN)) stageA(0, 0, (T2));                                            \
    LDA4(aHe, 1, 4, k0off);                                                    \
    SCHED0; MF16(aLe, bKe, 0);                                                 \
    /* ph6 */ SBAR;                                                            \
    if (!(FIN)) { stageA(0, 1, (T2)); stageB(0, 1, (T2)); }                    \
    LDB4(bKo, 1, k1off); LDA4(aLo, 1, 0, k1off);                               \
    SCHED0; MF16(aHe, bKe, 4);                                                 \
    /* ph7 */ SBAR;                                                            \
    LDA4(aHo, 1, 4, k1off);                                                    \
    SCHED0; MF16(aLo, bKo, 0);                                                 \
    /* ph8 */ SBAR;                                                            \
    if (!(FIN)) {                                                              \
      stageB(1, 0, (T3));                                                      \
      VMC(2);                                                                  \
      SBAR; /* all waves' T2 loads landed -> buf0 safe to read */              \
      LDB4(bKe, 0, k0off); LDA4(aLe, 0, 0, k0off);                             \
    }                                                                          \
    SCHED0; MF16(aHo, bKo, 4);                                                 \
  } while (0)

__global__ __launch_bounds__(512, 2) void gemm_bt(const uint16_t* __restrict__ A,
                                                  const uint16_t* __restrict__ B,
                                                  float* __restrict__ C) {
  __shared__ __align__(16) uint16_t Ab[2][BM * BK];   // 2 x 32 KiB
  __shared__ __align__(16) uint16_t Bb[2][BN * BK];   // 2 x 32 KiB

  const int tid = threadIdx.x;
  const int wv  = tid >> 6;
  const int l   = tid & 63;

  // XCD-bijective swizzle (1024 wgs % 8 == 0)
  const int wg = ((blockIdx.x & 7) << 7) | (blockIdx.x >> 3);
  const int tm = wg >> 4;          // 64 M-tiles
  const int tn = wg & 15;          // 16 N-tiles
  const int wm = wv >> 2;          // 0..1 -> rows wm*128
  const int wn = wv & 3;           // 0..3 -> cols wn*64

  // ---- staging source (inverse-swizzled global) ----
  const int t8  = tid >> 3;
  const int swz = (tid & 7) ^ ((tid >> 4) & 7);
  const uint16_t* sA = A + (size_t)(tm * BM + t8) * KDIM + swz * 8;
  const uint16_t* sB = B + (size_t)(tn * BN + t8) * KDIM + swz * 8;

  auto stageA = [&](int buf, int half, int tk) {
    #pragma unroll
    for (int j = 0; j < 2; ++j)
      __builtin_amdgcn_global_load_lds(
          (const __attribute__((address_space(1))) unsigned int*)
              (sA + (size_t)(half * 128 + j * 64) * KDIM + tk * BK),
          (__attribute__((address_space(3))) unsigned int*)
              ((char*)&Ab[buf][0] + half * 16384 + j * 8192 + wv * 1024),
          16, 0, 0);
  };
  auto stageB = [&](int buf, int half, int tk) {
    #pragma unroll
    for (int j = 0; j < 2; ++j)
      __builtin_amdgcn_global_load_lds(
          (const __attribute__((address_space(1))) unsigned int*)
              (sB + (size_t)(half * 128 + j * 64) * KDIM + tk * BK),
          (__attribute__((address_space(3))) unsigned int*)
              ((char*)&Bb[buf][0] + half * 16384 + j * 8192 + wv * 1024),
          16, 0, 0);
  };

  // ---- swizzled ds_read bases ----
  const int lA = l & 15, hi = l >> 4;
  const int xr = (lA >> 1) & 7;
  const int k0off = (hi ^ xr) * 16;
  const int k1off = k0off ^ 64;
  const char* aRd = (const char*)&Ab[0][0] + (wm * 128 + lA) * 128;
  const char* bRd = (const char*)&Bb[0][0] + (wn * 64 + lA) * 128;

  f32x4 acc[8][4] = {};
  short8 aLe[4], aHe[4], bKe[4], aLo[4], aHo[4], bKo[4];

  // ---- prologue: t0 fully + t1.B.h0; then pre-read ph1 frags ----
  stageA(0, 0, 0); stageA(0, 1, 0); stageB(0, 0, 0); stageB(0, 1, 0);
  stageB(1, 0, 1);
  VMC(2);            // own t0 loads landed; t1.B.h0 in flight
  SBAR;              // all waves' t0 landed -> buf0 readable
  LDB4(bKe, 0, k0off); LDA4(aLe, 0, 0, k0off);

  #pragma unroll 1
  for (int i = 0; i < NT / 2 - 1; ++i)     // i = 0..30
    ITER(2 * i + 1, 2 * i + 2, 2 * i + 3, 0);
  ITER(NT - 1, 0, 0, 1);                   // final iteration

  // ---- epilogue: C/D layout col = lane&15, row = (lane>>4)*4 + j ----
  float* Cp = C + (size_t)(tm * BM + wm * 128) * NDIM + tn * BN + wn * 64;
  const int co = hi * 4;
  #pragma unroll
  for (int m = 0; m < 8; ++m)
    #pragma unroll
    for (int n = 0; n < 4; ++n)
      #pragma unroll
      for (int j = 0; j < 4; ++j)
        Cp[(size_t)(m * 16 + co + j) * NDIM + n * 16 + lA] = acc[m][n][j];
}

extern "C" void kernel_launch(void* const* d_in, const int* in_sizes, int n_in,
                              void* d_out, int out_size, void* d_ws, size_t ws_size,
                              hipStream_t stream) {
  (void)in_sizes; (void)n_in; (void)out_size; (void)ws_size;
  const float* x = (const float*)d_in[0];   // (4,4096,4096) f32
  const float* w = (const float*)d_in[1];   // (4096,4096) f32
  float* out = (float*)d_out;               // (4,4096,4096) f32

  uint16_t* xb = (uint16_t*)d_ws;                       // 128 MiB
  uint16_t* wh = xb + (size_t)MDIM * KDIM;              // 32 MiB

  cvt_x_kernel<<<2048, 256, 0, stream>>>(x, xb, (int)((MDIM * (size_t)KDIM) / 8));
  fwht_w_kernel<<<(NDIM * KDIM) / 1024, 256, 0, stream>>>(w, wh);
  gemm_bt<<<(MDIM / BM) * (NDIM / BN), 512, 0, stream>>>(xb, wh, out);
}

// Round 6
// 613.332 us; speedup vs baseline: 1.1364x; 1.1364x over previous
//
#include <hip/hip_runtime.h>
#include <hip/hip_bf16.h>
#include <stdint.h>

// HadLinear: out = blockFWHT1024(x)/32 @ W^T  ==  x @ (blockFWHT1024(W rows)/32)^T
// (1) x f32->bf16, (2) Wh = FWHT(W)/32 -> bf16, (3) bf16 MFMA GEMM.
// GEMM R6: faithful m201 8-phase port. BM=BN=256, BK=64, 8 waves (2Mx4N),
// 2-buffer LDS (128 KiB), XOR chunk swizzle (both-sides), XCD swizzle.
// Phase = [ds_reads][stage 1 half-tile][lgkm hint][SBAR][lgkm0][16 MFMA][SBAR].
// Quadrant-major MFMA: q0=M0N0(12 rds) q1=M0N1(4) q2=M1N1(8) q3=M1N0(0, regs
// retained). VMC(4) post-MFMA at ph4/ph8 only; uniform 2 gloads staged/phase.

typedef __attribute__((ext_vector_type(8))) short    short8;
typedef __attribute__((ext_vector_type(4))) float    f32x4;
typedef __attribute__((ext_vector_type(8))) uint16_t u16x8;

static constexpr int MDIM = 16384;
static constexpr int NDIM = 4096;
static constexpr int KDIM = 4096;
static constexpr int BM = 256, BN = 256, BK = 64;
static constexpr int NT = KDIM / BK;   // 64 K-tiles, 32 iterations

__device__ __forceinline__ uint16_t f2bf(float f) {
  union { float f; uint32_t u; } c; c.f = f;
  uint32_t u = c.u;
  return (uint16_t)((u + 0x7FFFu + ((u >> 16) & 1u)) >> 16);
}

__global__ __launch_bounds__(256) void cvt_x_kernel(const float* __restrict__ x,
                                                    uint16_t* __restrict__ xb, int n8) {
  int stride = gridDim.x * blockDim.x;
  for (int t = blockIdx.x * blockDim.x + threadIdx.x; t < n8; t += stride) {
    const float4* p = reinterpret_cast<const float4*>(x + (size_t)t * 8);
    float4 a = p[0], b = p[1];
    u16x8 o;
    o[0] = f2bf(a.x); o[1] = f2bf(a.y); o[2] = f2bf(a.z); o[3] = f2bf(a.w);
    o[4] = f2bf(b.x); o[5] = f2bf(b.y); o[6] = f2bf(b.z); o[7] = f2bf(b.w);
    *reinterpret_cast<u16x8*>(xb + (size_t)t * 8) = o;
  }
}

__global__ __launch_bounds__(256) void fwht_w_kernel(const float* __restrict__ W,
                                                     uint16_t* __restrict__ Wh) {
  __shared__ float s[1024];
  const int tid = threadIdx.x;
  const size_t base = (size_t)blockIdx.x * 1024;
  reinterpret_cast<float4*>(s)[tid] = reinterpret_cast<const float4*>(W + base)[tid];
  __syncthreads();
  for (int h = 1; h < 1024; h <<= 1) {
    #pragma unroll
    for (int pp = 0; pp < 2; ++pp) {
      int p = tid + pp * 256;
      int q = p & (h - 1);
      int i = ((p - q) << 1) | q;
      float a = s[i], b = s[i + h];
      s[i] = a + b;
      s[i + h] = a - b;
    }
    __syncthreads();
  }
  #pragma unroll
  for (int pp = 0; pp < 4; ++pp) {
    int i = tid + pp * 256;
    Wh[base + i] = f2bf(s[i] * 0.03125f);
  }
}

// ---------------- 8-phase GEMM: C[M,N] = A[M,K] * B[N,K]^T ----------------
// LDS tile: 256 rows x 8 chunks(16B), chunk (r,c') holds global c = c'^((r>>1)&7).

#define FENCE asm volatile("" ::: "memory")
#define SBAR  do { FENCE; __builtin_amdgcn_s_barrier(); \
                   __builtin_amdgcn_sched_barrier(0); } while (0)
#define LGKM0 do { asm volatile("s_waitcnt lgkmcnt(0)" ::: "memory"); \
                   __builtin_amdgcn_sched_barrier(0); } while (0)
#define LGKM8 do { asm volatile("s_waitcnt lgkmcnt(8)" ::: "memory"); \
                   __builtin_amdgcn_sched_barrier(0); } while (0)
#define VMC(n) do { asm volatile("s_waitcnt vmcnt(" #n ")" ::: "memory"); \
                    __builtin_amdgcn_sched_barrier(0); } while (0)

// A quadrant MQ (rows MQ*64..+63 of wave tile): 8 frags [k*4+m]
#define LDAQ(DST, BUF, MQ)                                                     \
  do { _Pragma("unroll")                                                       \
    for (int k_ = 0; k_ < 2; ++k_)                                             \
      _Pragma("unroll")                                                        \
      for (int m_ = 0; m_ < 4; ++m_)                                           \
        DST[k_ * 4 + m_] = *(const short8*)(aRd + (BUF)*32768 +                \
            ((MQ)*64 + m_*16)*128 + (k_ ? k1off : k0off));                     \
  } while (0)

// B quadrant NQ (cols NQ*32..+31): 4 frags [k*2+n]
#define LDBQ(DST, BUF, NQ)                                                     \
  do { _Pragma("unroll")                                                       \
    for (int k_ = 0; k_ < 2; ++k_)                                             \
      _Pragma("unroll")                                                        \
      for (int n_ = 0; n_ < 2; ++n_)                                           \
        DST[k_ * 2 + n_] = *(const short8*)(bRd + (BUF)*32768 +                \
            ((NQ)*32 + n_*16)*128 + (k_ ? k1off : k0off));                     \
  } while (0)

// one quadrant: 4M x 2N x 2K = 16 MFMA
#define MFQ(AF, BF, MB, NB)                                                    \
  do { __builtin_amdgcn_s_setprio(1);                                          \
    _Pragma("unroll")                                                          \
    for (int k_ = 0; k_ < 2; ++k_)                                             \
      _Pragma("unroll")                                                        \
      for (int m_ = 0; m_ < 4; ++m_)                                           \
        _Pragma("unroll")                                                      \
        for (int n_ = 0; n_ < 2; ++n_)                                         \
          acc[(MB)+m_][(NB)+n_] = __builtin_amdgcn_mfma_f32_16x16x32_bf16(     \
              AF[k_*4+m_], BF[k_*2+n_], acc[(MB)+m_][(NB)+n_], 0, 0, 0);       \
    __builtin_amdgcn_s_setprio(0);                                             \
  } while (0)

// Iteration i: tile 2i in buf0 (ph1-4), T1=2i+1 in buf1 (ph5-8).
// Stage plan (1 half-tile = 2 gloads per phase):
//  ph1 T1.A.h1 | ph2 T1.B.h1 | ph3 T2.B.h0 | ph4 T2.A.h0
//  ph5 T2.A.h1 | ph6 T2.B.h1 | ph7 T3.B.h0 | ph8 T3.A.h0
// (T1.B.h0/T1.A.h0 staged at prev ph7/ph8.)  VMC(4) post-MFMA @ph4/ph8.
// Hazards: ph3/ph7 stage overwrites same-buf B.h0 only after all waves'
// B reads (ph1/ph2 resp. ph5/ph6) completed (trailing-barrier ordering);
// q3 reuses retained b0 regs, never re-reads LDS.
#define ITER(T1, T2, T3, FIN)                                                  \
  do {                                                                         \
    short8 a0[8], a1[8], b0[4], b1[4];                                         \
    /* ph1: buf0 q0 = M0 x N0 */                                               \
    LDAQ(a0, 0, 0); LDBQ(b0, 0, 0);                                            \
    stageA(1, 1, (T1));                                                        \
    LGKM8;                                                                     \
    SBAR; LGKM0; MFQ(a0, b0, 0, 0); SBAR;                                      \
    /* ph2: buf0 q1 = M0 x N1 */                                               \
    LDBQ(b1, 0, 1);                                                            \
    stageB(1, 1, (T1));                                                        \
    SBAR; LGKM0; MFQ(a0, b1, 0, 2); SBAR;                                      \
    /* ph3: buf0 q2 = M1 x N1 */                                               \
    LDAQ(a1, 0, 1);                                                            \
    if (!(FIN)) stageB(0, 0, (T2));                                            \
    SBAR; LGKM0; MFQ(a1, b1, 4, 2); SBAR;                                      \
    /* ph4: buf0 q3 = M1 x N0 (0 reads, regs retained) */                      \
    if (!(FIN)) stageA(0, 0, (T2));                                            \
    MFQ(a1, b0, 4, 0);                                                         \
    if (FIN) { VMC(0); } else { VMC(4); }                                      \
    SBAR;                                                                      \
    /* ph5: buf1 q0 */                                                         \
    LDAQ(a0, 1, 0); LDBQ(b0, 1, 0);                                            \
    if (!(FIN)) stageA(0, 1, (T2));                                            \
    LGKM8;                                                                     \
    SBAR; LGKM0; MFQ(a0, b0, 0, 0); SBAR;                                      \
    /* ph6: buf1 q1 */                                                         \
    LDBQ(b1, 1, 1);                                                            \
    if (!(FIN)) stageB(0, 1, (T2));                                            \
    SBAR; LGKM0; MFQ(a0, b1, 0, 2); SBAR;                                      \
    /* ph7: buf1 q2 */                                                         \
    LDAQ(a1, 1, 1);                                                            \
    if (!(FIN)) stageB(1, 0, (T3));                                            \
    SBAR; LGKM0; MFQ(a1, b1, 4, 2); SBAR;                                      \
    /* ph8: buf1 q3 (0 reads) */                                               \
    if (!(FIN)) stageA(1, 0, (T3));                                            \
    MFQ(a1, b0, 4, 0);                                                         \
    if (!(FIN)) { VMC(4); SBAR; }                                              \
  } while (0)

__global__ __launch_bounds__(512, 2) void gemm_bt(const uint16_t* __restrict__ A,
                                                  const uint16_t* __restrict__ B,
                                                  float* __restrict__ C) {
  __shared__ __align__(16) uint16_t Ab[2][BM * BK];   // 2 x 32 KiB
  __shared__ __align__(16) uint16_t Bb[2][BN * BK];   // 2 x 32 KiB

  const int tid = threadIdx.x;
  const int wv  = tid >> 6;
  const int l   = tid & 63;

  // XCD-bijective swizzle (1024 wgs % 8 == 0)
  const int wg = ((blockIdx.x & 7) << 7) | (blockIdx.x >> 3);
  const int tm = wg >> 4;          // 64 M-tiles
  const int tn = wg & 15;          // 16 N-tiles
  const int wm = wv >> 2;          // 0..1 -> rows wm*128
  const int wn = wv & 3;           // 0..3 -> cols wn*64

  // ---- staging source (inverse-swizzled global) ----
  // linear chunk n = j*512 + tid -> r = j*64 + (tid>>3), c' = tid&7
  // source chunk c = c' ^ ((r>>1)&7) = (tid&7) ^ ((tid>>4)&7)
  const int t8  = tid >> 3;
  const int swz = (tid & 7) ^ ((tid >> 4) & 7);
  const uint16_t* sA = A + (size_t)(tm * BM + t8) * KDIM + swz * 8;
  const uint16_t* sB = B + (size_t)(tn * BN + t8) * KDIM + swz * 8;

  auto stageA = [&](int buf, int half, int tk) {
    #pragma unroll
    for (int j = 0; j < 2; ++j)
      __builtin_amdgcn_global_load_lds(
          (const __attribute__((address_space(1))) unsigned int*)
              (sA + (size_t)(half * 128 + j * 64) * KDIM + tk * BK),
          (__attribute__((address_space(3))) unsigned int*)
              ((char*)&Ab[buf][0] + half * 16384 + j * 8192 + wv * 1024),
          16, 0, 0);
  };
  auto stageB = [&](int buf, int half, int tk) {
    #pragma unroll
    for (int j = 0; j < 2; ++j)
      __builtin_amdgcn_global_load_lds(
          (const __attribute__((address_space(1))) unsigned int*)
              (sB + (size_t)(half * 128 + j * 64) * KDIM + tk * BK),
          (__attribute__((address_space(3))) unsigned int*)
              ((char*)&Bb[buf][0] + half * 16384 + j * 8192 + wv * 1024),
          16, 0, 0);
  };

  // ---- swizzled ds_read bases ----
  const int lA = l & 15, hi = l >> 4;
  const int xr = (lA >> 1) & 7;
  const int k0off = (hi ^ xr) * 16;
  const int k1off = k0off ^ 64;
  const char* aRd = (const char*)&Ab[0][0] + (wm * 128 + lA) * 128;
  const char* bRd = (const char*)&Bb[0][0] + (wn * 64 + lA) * 128;

  f32x4 acc[8][4] = {};

  // ---- prologue: T0 fully (8 loads), then T1.B.h0 + T1.A.h0 (4 loads) ----
  stageA(0, 0, 0); stageA(0, 1, 0); stageB(0, 0, 0); stageB(0, 1, 0);
  stageB(1, 0, 1); stageA(1, 0, 1);
  VMC(4);            // T0's 8 (oldest) landed; T1's 4 in flight
  SBAR;              // all waves' T0 landed -> buf0 readable

  #pragma unroll 1
  for (int i = 0; i < NT / 2 - 1; ++i)     // i = 0..30
    ITER(2 * i + 1, 2 * i + 2, 2 * i + 3, 0);
  ITER(NT - 1, 0, 0, 1);                   // final iteration

  // ---- epilogue: C/D layout col = lane&15, row = (lane>>4)*4 + j ----
  float* Cp = C + (size_t)(tm * BM + wm * 128) * NDIM + tn * BN + wn * 64;
  const int co = hi * 4;
  #pragma unroll
  for (int m = 0; m < 8; ++m)
    #pragma unroll
    for (int n = 0; n < 4; ++n)
      #pragma unroll
      for (int j = 0; j < 4; ++j)
        Cp[(size_t)(m * 16 + co + j) * NDIM + n * 16 + lA] = acc[m][n][j];
}

extern "C" void kernel_launch(void* const* d_in, const int* in_sizes, int n_in,
                              void* d_out, int out_size, void* d_ws, size_t ws_size,
                              hipStream_t stream) {
  (void)in_sizes; (void)n_in; (void)out_size; (void)ws_size;
  const float* x = (const float*)d_in[0];   // (4,4096,4096) f32
  const float* w = (const float*)d_in[1];   // (4096,4096) f32
  float* out = (float*)d_out;               // (4,4096,4096) f32

  uint16_t* xb = (uint16_t*)d_ws;                       // 128 MiB
  uint16_t* wh = xb + (size_t)MDIM * KDIM;              // 32 MiB

  cvt_x_kernel<<<2048, 256, 0, stream>>>(x, xb, (int)((MDIM * (size_t)KDIM) / 8));
  fwht_w_kernel<<<(NDIM * KDIM) / 1024, 256, 0, stream>>>(w, wh);
  gemm_bt<<<(MDIM / BM) * (NDIM / BN), 512, 0, stream>>>(xb, wh, out);
}

// Round 7
// 604.925 us; speedup vs baseline: 1.1522x; 1.0139x over previous
//
#include <hip/hip_runtime.h>
#include <hip/hip_bf16.h>
#include <stdint.h>

// HadLinear: out = blockFWHT1024(x)/32 @ W^T  ==  x @ (blockFWHT1024(W rows)/32)^T
// (1) x f32->bf16, (2) Wh = FWHT(W)/32 -> bf16, (3) bf16 MFMA GEMM.
// GEMM R7 = R4 schedule (single barrier/phase, VMC post-MFMA) +
//   (a) smoothed staging: A staged in read-group units (rows {g*64..+63} u
//       {g*64+128..+191}) so every stage targets a region whose reads
//       finished >=1 barrier earlier; min 2-phase landing lead; VMC(4).
//   (b) per-XCD concurrent block set shaped 8tm x 4tn for L2 reuse.

typedef __attribute__((ext_vector_type(8))) short    short8;
typedef __attribute__((ext_vector_type(4))) float    f32x4;
typedef __attribute__((ext_vector_type(8))) uint16_t u16x8;

static constexpr int MDIM = 16384;
static constexpr int NDIM = 4096;
static constexpr int KDIM = 4096;
static constexpr int BM = 256, BN = 256, BK = 64;
static constexpr int NT = KDIM / BK;   // 64 K-tiles, 32 iterations

__device__ __forceinline__ uint16_t f2bf(float f) {
  union { float f; uint32_t u; } c; c.f = f;
  uint32_t u = c.u;
  return (uint16_t)((u + 0x7FFFu + ((u >> 16) & 1u)) >> 16);
}

__global__ __launch_bounds__(256) void cvt_x_kernel(const float* __restrict__ x,
                                                    uint16_t* __restrict__ xb, int n8) {
  int stride = gridDim.x * blockDim.x;
  for (int t = blockIdx.x * blockDim.x + threadIdx.x; t < n8; t += stride) {
    const float4* p = reinterpret_cast<const float4*>(x + (size_t)t * 8);
    float4 a = p[0], b = p[1];
    u16x8 o;
    o[0] = f2bf(a.x); o[1] = f2bf(a.y); o[2] = f2bf(a.z); o[3] = f2bf(a.w);
    o[4] = f2bf(b.x); o[5] = f2bf(b.y); o[6] = f2bf(b.z); o[7] = f2bf(b.w);
    *reinterpret_cast<u16x8*>(xb + (size_t)t * 8) = o;
  }
}

__global__ __launch_bounds__(256) void fwht_w_kernel(const float* __restrict__ W,
                                                     uint16_t* __restrict__ Wh) {
  __shared__ float s[1024];
  const int tid = threadIdx.x;
  const size_t base = (size_t)blockIdx.x * 1024;
  reinterpret_cast<float4*>(s)[tid] = reinterpret_cast<const float4*>(W + base)[tid];
  __syncthreads();
  for (int h = 1; h < 1024; h <<= 1) {
    #pragma unroll
    for (int pp = 0; pp < 2; ++pp) {
      int p = tid + pp * 256;
      int q = p & (h - 1);
      int i = ((p - q) << 1) | q;
      float a = s[i], b = s[i + h];
      s[i] = a + b;
      s[i + h] = a - b;
    }
    __syncthreads();
  }
  #pragma unroll
  for (int pp = 0; pp < 4; ++pp) {
    int i = tid + pp * 256;
    Wh[base + i] = f2bf(s[i] * 0.03125f);
  }
}

// ---------------- 8-phase GEMM: C[M,N] = A[M,K] * B[N,K]^T ----------------
// LDS tile: 256 rows x 8 chunks(16B), chunk (r,c') holds global c = c'^((r>>1)&7).

#define FENCE asm volatile("" ::: "memory")
#define SBAR  do { FENCE; __builtin_amdgcn_s_barrier(); \
                   __builtin_amdgcn_sched_barrier(0); } while (0)
#define LGKM0 do { asm volatile("s_waitcnt lgkmcnt(0)" ::: "memory"); \
                   __builtin_amdgcn_sched_barrier(0); } while (0)
#define VMC(n) do { asm volatile("s_waitcnt vmcnt(" #n ")" ::: "memory"); \
                    __builtin_amdgcn_sched_barrier(0); } while (0)

#define LDA4(DST, BUF, MLO, KOFF)                                              \
  do { _Pragma("unroll")                                                       \
    for (int m_ = 0; m_ < 4; ++m_)                                             \
      DST[m_] = *(const short8*)(aRd + (BUF)*32768 + ((MLO)+m_)*2048 + (KOFF)); \
  } while (0)

#define LDB4(DST, BUF, KOFF)                                                   \
  do { _Pragma("unroll")                                                       \
    for (int n_ = 0; n_ < 4; ++n_)                                             \
      DST[n_] = *(const short8*)(bRd + (BUF)*32768 + n_*2048 + (KOFF));        \
  } while (0)

#define MF16(AF, BF, MB)                                                       \
  do { __builtin_amdgcn_s_setprio(1);                                          \
    _Pragma("unroll")                                                          \
    for (int m_ = 0; m_ < 4; ++m_)                                             \
      _Pragma("unroll")                                                        \
      for (int n_ = 0; n_ < 4; ++n_)                                           \
        acc[(MB)+m_][n_] = __builtin_amdgcn_mfma_f32_16x16x32_bf16(            \
            AF[m_], BF[n_], acc[(MB)+m_][n_], 0, 0, 0);                        \
    __builtin_amdgcn_s_setprio(0);                                             \
  } while (0)

// Read schedule (R4): ph1 B.k0+aL.k0 | ph2 aH.k0 | ph3 B.k1+aL.k1 | ph4 aH.k1
// (aL rows {0-63,128-191} block-level; aH rows {64-127,192-255}).
// Stage schedule (v4): T1=2i+1 (buf1), T2=2i+2 (buf0), T3=2i+3 (buf1):
//  ph1 T1.A.g1 | ph2 T1.B.h1 | ph4 T2.B.h0 + T2.A.g0 | ph5 T2.A.g1
//  ph6 T2.B.h1 | ph8 T3.B.h0 + T3.A.g0
// A group g = rows {g*64..+63} u {g*64+128..+191}  (matches aL/aH read groups:
// stage at ph4 targets g0 = aL rows, read last at ph3 -> safe while ph4 reads aH).
// VMC(4) post-MFMA @ph4 (drains T1 before ph5 reads buf1) and @ph8 (drains T2).
#define ITER(T1, T2, T3, FIN)                                                  \
  do {                                                                         \
    short8 aL[4], aH[4], bK[4];                                                \
    /* ph1 */ SBAR;                                                            \
    LDB4(bK, 0, k0off); LDA4(aL, 0, 0, k0off);                                 \
    stageAg(1, 1, (T1));                                                       \
    LGKM0; MF16(aL, bK, 0);                                                    \
    /* ph2 */ SBAR;                                                            \
    LDA4(aH, 0, 4, k0off);                                                     \
    stageB(1, 1, (T1));                                                        \
    LGKM0; MF16(aH, bK, 4);                                                    \
    /* ph3 */ SBAR;                                                            \
    LDB4(bK, 0, k1off); LDA4(aL, 0, 0, k1off);                                 \
    LGKM0; MF16(aL, bK, 0);                                                    \
    /* ph4 */ SBAR;                                                            \
    LDA4(aH, 0, 4, k1off);                                                     \
    if (!(FIN)) { stageB(0, 0, (T2)); stageAg(0, 0, (T2)); }                   \
    LGKM0; MF16(aH, bK, 4);                                                    \
    if (FIN) { VMC(0); } else { VMC(4); }                                      \
    /* ph5 */ SBAR;                                                            \
    LDB4(bK, 1, k0off); LDA4(aL, 1, 0, k0off);                                 \
    if (!(FIN)) stageAg(0, 1, (T2));                                           \
    LGKM0; MF16(aL, bK, 0);                                                    \
    /* ph6 */ SBAR;                                                            \
    LDA4(aH, 1, 4, k0off);                                                     \
    if (!(FIN)) stageB(0, 1, (T2));                                            \
    LGKM0; MF16(aH, bK, 4);                                                    \
    /* ph7 */ SBAR;                                                            \
    LDB4(bK, 1, k1off); LDA4(aL, 1, 0, k1off);                                 \
    LGKM0; MF16(aL, bK, 0);                                                    \
    /* ph8 */ SBAR;                                                            \
    LDA4(aH, 1, 4, k1off);                                                     \
    if (!(FIN)) { stageB(1, 0, (T3)); stageAg(1, 0, (T3)); }                   \
    LGKM0; MF16(aH, bK, 4);                                                    \
    if (!(FIN)) { VMC(4); }                                                    \
  } while (0)

__global__ __launch_bounds__(512, 2) void gemm_bt(const uint16_t* __restrict__ A,
                                                  const uint16_t* __restrict__ B,
                                                  float* __restrict__ C) {
  __shared__ __align__(16) uint16_t Ab[2][BM * BK];   // 2 x 32 KiB
  __shared__ __align__(16) uint16_t Bb[2][BN * BK];   // 2 x 32 KiB

  const int tid = threadIdx.x;
  const int wv  = tid >> 6;
  const int l   = tid & 63;

  // XCD-aware mapping, per-XCD concurrent set = 8tm x 4tn (bijective):
  // b -> xcd = b&7, r = b>>3; sub = r>>5 (tn quad), s = r&31: stm=s>>2, stn=s&3
  const int xcd = blockIdx.x & 7;
  const int r_  = blockIdx.x >> 3;
  const int tm  = xcd * 8 + ((r_ & 31) >> 2);   // 64 M-tiles
  const int tn  = (r_ >> 5) * 4 + (r_ & 3);     // 16 N-tiles
  const int wm  = wv >> 2;          // 0..1 -> rows wm*128
  const int wn  = wv & 3;           // 0..3 -> cols wn*64

  // ---- staging source (inverse-swizzled global) ----
  // linear chunk n = j*512 + tid -> r = j*64 + (tid>>3), c' = tid&7
  // source chunk c = c' ^ ((r>>1)&7) = (tid&7) ^ ((tid>>4)&7)
  const int t8  = tid >> 3;
  const int swz = (tid & 7) ^ ((tid >> 4) & 7);
  const uint16_t* sA = A + (size_t)(tm * BM + t8) * KDIM + swz * 8;
  const uint16_t* sB = B + (size_t)(tn * BN + t8) * KDIM + swz * 8;

  // A read-group staging: g covers rows {g*64 + j*128 + 0..63}, j = 0,1
  auto stageAg = [&](int buf, int g, int tk) {
    #pragma unroll
    for (int j = 0; j < 2; ++j)
      __builtin_amdgcn_global_load_lds(
          (const __attribute__((address_space(1))) unsigned int*)
              (sA + (size_t)(g * 64 + j * 128) * KDIM + tk * BK),
          (__attribute__((address_space(3))) unsigned int*)
              ((char*)&Ab[buf][0] + g * 8192 + j * 16384 + wv * 1024),
          16, 0, 0);
  };
  auto stageB = [&](int buf, int half, int tk) {
    #pragma unroll
    for (int j = 0; j < 2; ++j)
      __builtin_amdgcn_global_load_lds(
          (const __attribute__((address_space(1))) unsigned int*)
              (sB + (size_t)(half * 128 + j * 64) * KDIM + tk * BK),
          (__attribute__((address_space(3))) unsigned int*)
              ((char*)&Bb[buf][0] + half * 16384 + j * 8192 + wv * 1024),
          16, 0, 0);
  };

  // ---- swizzled ds_read bases ----
  const int lA = l & 15, hi = l >> 4;
  const int xr = (lA >> 1) & 7;
  const int k0off = (hi ^ xr) * 16;
  const int k1off = k0off ^ 64;
  const char* aRd = (const char*)&Ab[0][0] + (wm * 128 + lA) * 128;
  const char* bRd = (const char*)&Bb[0][0] + (wn * 64 + lA) * 128;

  f32x4 acc[8][4] = {};

  // ---- prologue: T0 full (8 loads) + T1.B.h0 + T1.A.g0 (4 loads) ----
  stageAg(0, 0, 0); stageAg(0, 1, 0); stageB(0, 0, 0); stageB(0, 1, 0);
  stageB(1, 0, 1);  stageAg(1, 0, 1);
  VMC(4);            // T0's 8 (oldest) landed; T1's 4 in flight

  #pragma unroll 1
  for (int i = 0; i < NT / 2 - 1; ++i)     // i = 0..30
    ITER(2 * i + 1, 2 * i + 2, 2 * i + 3, 0);
  ITER(NT - 1, 0, 0, 1);                   // final iteration

  // ---- epilogue: C/D layout col = lane&15, row = (lane>>4)*4 + j ----
  float* Cp = C + (size_t)(tm * BM + wm * 128) * NDIM + tn * BN + wn * 64;
  const int co = hi * 4;
  #pragma unroll
  for (int m = 0; m < 8; ++m)
    #pragma unroll
    for (int n = 0; n < 4; ++n)
      #pragma unroll
      for (int j = 0; j < 4; ++j)
        Cp[(size_t)(m * 16 + co + j) * NDIM + n * 16 + lA] = acc[m][n][j];
}

extern "C" void kernel_launch(void* const* d_in, const int* in_sizes, int n_in,
                              void* d_out, int out_size, void* d_ws, size_t ws_size,
                              hipStream_t stream) {
  (void)in_sizes; (void)n_in; (void)out_size; (void)ws_size;
  const float* x = (const float*)d_in[0];   // (4,4096,4096) f32
  const float* w = (const float*)d_in[1];   // (4096,4096) f32
  float* out = (float*)d_out;               // (4,4096,4096) f32

  uint16_t* xb = (uint16_t*)d_ws;                       // 128 MiB
  uint16_t* wh = xb + (size_t)MDIM * KDIM;              // 32 MiB

  cvt_x_kernel<<<2048, 256, 0, stream>>>(x, xb, (int)((MDIM * (size_t)KDIM) / 8));
  fwht_w_kernel<<<(NDIM * KDIM) / 1024, 256, 0, stream>>>(w, wh);
  gemm_bt<<<(MDIM / BM) * (NDIM / BN), 512, 0, stream>>>(xb, wh, out);
}